// Round 1
// baseline (351.832 us; speedup 1.0000x reference)
//
#include <hip/hip_runtime.h>
#include <hip/hip_bf16.h>

#define BATCH 128
#define TIME 512
#define NUM_CLASSES 1024
#define BLANK (NUM_CLASSES - 1)
#define DUMMY_WORD 2

// Kernel 1: argmax over V=1024 per (b,t). One wave (64 lanes) per position.
// Each lane: 4 float4 loads (16 floats), element base = 4*(lane + 64*k).
// Tie-break = first (lowest) index, matching jnp.argmax.
__global__ __launch_bounds__(256) void argmax_kernel(
    const float* __restrict__ in, int* __restrict__ ids) {
    int wid = blockIdx.x * 4 + (threadIdx.x >> 6);   // (b,t) flat index
    int lane = threadIdx.x & 63;
    const float4* p = (const float4*)(in + (size_t)wid * NUM_CLASSES);

    float best = -1e30f;
    int bidx = 0;
#pragma unroll
    for (int k = 0; k < 4; k++) {
        float4 v = p[lane + k * 64];
        int base = 4 * (lane + k * 64);
        // in-lane indices increase over k and components: strict > keeps first max
        if (v.x > best) { best = v.x; bidx = base; }
        if (v.y > best) { best = v.y; bidx = base + 1; }
        if (v.z > best) { best = v.z; bidx = base + 2; }
        if (v.w > best) { best = v.w; bidx = base + 3; }
    }
    // butterfly reduce (val, idx): greater val wins; equal val -> smaller idx
#pragma unroll
    for (int m = 32; m >= 1; m >>= 1) {
        float ov = __shfl_xor(best, m, 64);
        int   oi = __shfl_xor(bidx, m, 64);
        if (ov > best || (ov == best && oi < bidx)) { best = ov; bidx = oi; }
    }
    if (lane == 0) ids[wid] = bidx;
}

// Kernel 2: per-row stable compaction of non-blank tokens, in place.
// One wave per row; lane i owns t in [8i, 8i+8). All loads issue before any
// store within the wave's single instruction stream -> in-place is safe.
__global__ __launch_bounds__(64) void compact_kernel(
    int* __restrict__ ids, int* __restrict__ counts) {
    int b = blockIdx.x;
    int lane = threadIdx.x;
    int* row = ids + b * TIME;

    const int4* r4 = (const int4*)row;
    int4 a = r4[lane * 2];
    int4 c = r4[lane * 2 + 1];
    int vals[8] = {a.x, a.y, a.z, a.w, c.x, c.y, c.z, c.w};

    int cnt = 0;
#pragma unroll
    for (int j = 0; j < 8; j++) cnt += (vals[j] != BLANK);

    // inclusive scan of per-lane counts
    int incl = cnt;
#pragma unroll
    for (int off = 1; off < 64; off <<= 1) {
        int n = __shfl_up(incl, off, 64);
        if (lane >= off) incl += n;
    }
    int pos = incl - cnt;  // exclusive prefix = stable write offset
#pragma unroll
    for (int j = 0; j < 8; j++) {
        if (vals[j] != BLANK) { row[pos] = vals[j]; pos++; }
    }
    if (lane == 63) counts[b] = incl;  // total nonblank count for row
}

// Kernel 3: out[b][t] = compacted (already in place, t < cnt)
//                      | -1 (cnt <= t < max_len) | DUMMY_WORD (t >= max_len)
__global__ __launch_bounds__(512) void finalize_kernel(
    const int* __restrict__ counts, int* __restrict__ out) {
    __shared__ int smem[BATCH];
    __shared__ int s_max;
    int b = blockIdx.x;
    int t = threadIdx.x;
    if (t < BATCH) smem[t] = counts[t];
    __syncthreads();
    if (t == 0) {
        int m = 0;
        for (int i = 0; i < BATCH; i++) m = max(m, smem[i]);
        s_max = m;
    }
    __syncthreads();
    int cnt = smem[b];
    if (t >= cnt) out[b * TIME + t] = (t < s_max) ? -1 : DUMMY_WORD;
}

extern "C" void kernel_launch(void* const* d_in, const int* in_sizes, int n_in,
                              void* d_out, int out_size, void* d_ws, size_t ws_size,
                              hipStream_t stream) {
    const float* in = (const float*)d_in[0];
    int* out = (int*)d_out;            // [B, T] int32; reused as ids scratch
    int* counts = (int*)d_ws;          // [B] int32

    // 65536 (b,t) positions, 4 waves per 256-thread block
    argmax_kernel<<<(BATCH * TIME) / 4, 256, 0, stream>>>(in, out);
    compact_kernel<<<BATCH, 64, 0, stream>>>(out, counts);
    finalize_kernel<<<BATCH, 512, 0, stream>>>(counts, out);
}